// Round 5
// baseline (267.466 us; speedup 1.0000x reference)
//
#include <hip/hip_runtime.h>
#include <math.h>

typedef float f4 __attribute__((ext_vector_type(4)));

constexpr int N_ELEM = 4096;
constexpr float LOG2E = 1.4426950408889634f;
constexpr float LN2   = 0.6931471805599453f;

// sigmoid via exp2/rcp (boundary values only)
__device__ __forceinline__ float sigmoid_fast(float x) {
    float e2 = __builtin_amdgcn_exp2f(-fabsf(x) * LOG2E);
    float u  = 1.0f + e2;
    return ((x >= 0.0f) ? 1.0f : e2) * __builtin_amdgcn_rcpf(u);
}

// One block per row. Wave w owns contiguous segment [w*1024, w*1024+1024).
// Lane l, chunk c owns float4 at seg + 256c + 4l (lane-contiguous, coalesced).
// All math in log2 domain; ln2 folded into the final scale.
// Last-finishing block reduces all row partials -> d_out (single kernel).
__global__ __launch_bounds__(256) void loss_kernel(
        const float* __restrict__ in,
        const float* __restrict__ tgt,
        float* __restrict__ partials,
        unsigned int* __restrict__ counter,
        float* __restrict__ out,
        int nrows, float invN, float invB) {
    const int t = threadIdx.x;
    const int w = t >> 6;
    const int l = t & 63;
    const int seg = w << 10;
    const int b = blockIdx.x;
    const float* __restrict__ row = in + (size_t)b * N_ELEM;

    // ---- issue ALL global loads up front (max memory-level parallelism) ----
    const int base = seg + (l << 2);
    f4 v0 = *reinterpret_cast<const f4*>(row + base);
    f4 v1 = *reinterpret_cast<const f4*>(row + base + 256);
    f4 v2 = *reinterpret_cast<const f4*>(row + base + 512);
    f4 v3 = *reinterpret_cast<const f4*>(row + base + 768);
    float xl = row[(seg > 0) ? seg - 1 : 0];
    float xr = row[(seg + 1024 < N_ELEM) ? seg + 1024 : N_ELEM - 1];
    float tb = tgt[b];

    float pl_wave = (seg > 0)             ? sigmoid_fast(xl) : 0.0f;
    float pr_wave = (seg + 1024 < N_ELEM) ? sigmoid_fast(xr) : 0.0f;

    float accH = 0.0f;     // sum p*(pl+pr)*log2(p)
    float accL = 0.0f;     // sum log2(p) + log2(1-p)
    float prev_p3 = 0.0f;
    float dc = 0.0f;       // lane-63 deferred coefficient p3*lp3

    f4 vv[4] = {v0, v1, v2, v3};
#pragma unroll
    for (int c = 0; c < 4; ++c) {
        f4 v = vv[c];
        float p[4], lp[4];
#pragma unroll
        for (int j = 0; j < 4; ++j) {
            float x   = v[j];
            float m   = -fabsf(x) * LOG2E;                    // log2 e^{-|x|}
            float e2  = __builtin_amdgcn_exp2f(m);            // e^{-|x|}
            float u   = 1.0f + e2;
            float L2  = __builtin_amdgcn_logf(u);             // log2(u), u in [1,2]
            float lp2 = fmaf(fminf(x, 0.0f), LOG2E, -L2);     // log2 p
            p[j]  = __builtin_amdgcn_exp2f(lp2);              // sigmoid(x)
            lp[j] = lp2;
            accL += fmaf(-2.0f, L2, m);                       // log2 p + log2(1-p)
        }

        // Resolve previous chunk's lane-63 deferred right-neighbor term.
        float b0 = __shfl(p[0], 0);
        accH += dc * b0;

        // In-wave neighbor exchange (all lanes execute shuffles).
        float leftP  = __shfl_up(p[3], 1);      // lane l-1's p3
        float rightP = __shfl_down(p[0], 1);    // lane l+1's p0
        float p3b    = __shfl(prev_p3, 63);     // prev chunk lane-63 p3
        if (l == 0)  leftP  = (c == 0) ? pl_wave : p3b;
        if (l == 63) rightP = 0.0f;             // deferred via dc

        accH += p[0] * (leftP + p[1]) * lp[0];
        accH += p[1] * (p[0] + p[2])  * lp[1];
        accH += p[2] * (p[1] + p[3])  * lp[2];
        accH += p[3] * (p[2] + rightP)* lp[3];

        dc = (l == 63) ? p[3] * lp[3] : 0.0f;
        prev_p3 = p[3];
    }
    accH += dc * pr_wave;

    float total = (-tb * LN2) * (accH + invN * accL);

    // Block reduction.
#pragma unroll
    for (int off = 32; off; off >>= 1) total += __shfl_down(total, off);
    __shared__ float sm[4];
    if (l == 0) sm[w] = total;
    __syncthreads();

    __shared__ int lastflag;
    if (t == 0) {
        float s = (sm[0] + sm[1]) + (sm[2] + sm[3]);
        __hip_atomic_store(&partials[b], s, __ATOMIC_RELAXED,
                           __HIP_MEMORY_SCOPE_AGENT);
        unsigned int cnt = __hip_atomic_fetch_add(counter, 1u, __ATOMIC_ACQ_REL,
                                                  __HIP_MEMORY_SCOPE_AGENT);
        lastflag = (cnt == (unsigned)nrows - 1) ? 1 : 0;
    }
    __syncthreads();

    if (lastflag) {
        // Finisher: deterministic fixed-order sum of all partials.
        float acc = 0.0f;
        for (int i = t; i < nrows; i += 256)
            acc += __hip_atomic_load(&partials[i], __ATOMIC_RELAXED,
                                     __HIP_MEMORY_SCOPE_AGENT);
#pragma unroll
        for (int off = 32; off; off >>= 1) acc += __shfl_down(acc, off);
        __shared__ float sm2[4];
        if (l == 0) sm2[w] = acc;
        __syncthreads();
        if (t == 0) out[0] = ((sm2[0] + sm2[1]) + (sm2[2] + sm2[3])) * invB;
    }
}

extern "C" void kernel_launch(void* const* d_in, const int* in_sizes, int n_in,
                              void* d_out, int out_size, void* d_ws, size_t ws_size,
                              hipStream_t stream) {
    const float* inputs  = (const float*)d_in[0];
    const float* targets = (const float*)d_in[1];
    float* out = (float*)d_out;

    const int B = in_sizes[1];   // 8192 rows

    float* partials = (float*)d_ws;                       // B floats
    unsigned int* counter = (unsigned int*)((char*)d_ws + (size_t)B * sizeof(float));

    // Zero the completion counter each call (graph-capture-safe, deterministic).
    hipMemsetAsync(counter, 0, sizeof(unsigned int), stream);

    loss_kernel<<<B, 256, 0, stream>>>(
        inputs, targets, partials, counter, out,
        B, 1.0f / (float)N_ELEM, 1.0f / (float)B);
}

// Round 6
// 32.530 us; speedup vs baseline: 8.2220x; 8.2220x over previous
//
#include <hip/hip_runtime.h>
#include <math.h>

typedef float f4 __attribute__((ext_vector_type(4)));

constexpr int N_ELEM = 4096;
constexpr int NCHUNK = 16;          // 16 chunks x 256 elems (64 lanes x 4)
constexpr int ROWS_PER_BLOCK = 4;   // one wave per row, 4 waves per block
constexpr float LOG2E = 1.4426950408889634f;
constexpr float LN2   = 0.6931471805599453f;

// One WAVE per row. Lane l, chunk c owns float4 at 256c + 4l (lane-contiguous).
// All neighbor exchange is in-wave shuffles + deferred-coefficient trick:
// no LDS row, no barriers, no boundary reloads.
// Math in log2 domain: e2 = 2^(-|x|*log2e), L2 = log2(1+e2),
//   log2 p = min(x,0)*log2e - L2 ; log2 p + log2(1-p) = -|x|*log2e - 2*L2
//   p = (x>=0 ? 1 : e2) * rcp(1+e2)
__global__ __launch_bounds__(256) void row_loss_kernel(
        const float* __restrict__ in,
        const float* __restrict__ tgt,
        float* __restrict__ partials,
        float invN) {
    const int t = threadIdx.x;
    const int w = t >> 6;
    const int l = t & 63;
    const int row_idx = blockIdx.x * ROWS_PER_BLOCK + w;
    const float* __restrict__ row = in + (size_t)row_idx * N_ELEM;

    const float tb = tgt[row_idx];

    f4 v[NCHUNK];  // statically indexed after full unroll -> registers

    // Prefetch depth 8: issue first 8 chunk loads up front.
#pragma unroll
    for (int c = 0; c < 8; ++c)
        v[c] = *reinterpret_cast<const f4*>(row + (c << 8) + (l << 2));

    float accH = 0.0f;   // sum p*(p_left+p_right)*log2(p)
    float accL = 0.0f;   // sum log2 p + log2(1-p)
    float prev_p3 = 0.0f;
    float dc = 0.0f;     // lane-63 deferred coefficient p3*lp3

#pragma unroll
    for (int c = 0; c < NCHUNK; ++c) {
        if (c + 8 < NCHUNK)   // keep 8 loads in flight
            v[c + 8] = *reinterpret_cast<const f4*>(row + ((c + 8) << 8) + (l << 2));

        float p[4], lp[4];
#pragma unroll
        for (int j = 0; j < 4; ++j) {
            float x   = v[c][j];
            float m   = -fabsf(x) * LOG2E;                 // log2 e^{-|x|}
            float e2  = __builtin_amdgcn_exp2f(m);         // e^{-|x|}
            float u   = 1.0f + e2;
            float L2  = __builtin_amdgcn_logf(u);          // log2(u), u in [1,2]
            float ru  = __builtin_amdgcn_rcpf(u);
            p[j]  = ((x >= 0.0f) ? 1.0f : e2) * ru;        // sigmoid(x)
            lp[j] = fmaf(fminf(x, 0.0f), LOG2E, -L2);      // log2 p
            accL += fmaf(-2.0f, L2, m);                    // log2 p + log2(1-p)
        }

        // Resolve prev chunk's lane-63 deferred right-neighbor term:
        // its right neighbor is this chunk's lane-0 p0.
        float b0 = __shfl(p[0], 0);
        accH += dc * b0;

        // In-wave neighbor exchange.
        float leftP  = __shfl_up(p[3], 1);       // lane l-1's p3 = p[idx-1]
        float rightP = __shfl_down(p[0], 1);     // lane l+1's p0 = p[idx+4]
        float p3b    = __shfl(prev_p3, 63);      // prev chunk lane-63's p3
        if (l == 0)  leftP  = (c == 0) ? 0.0f : p3b;   // row start pads 0
        if (l == 63) rightP = 0.0f;                     // deferred via dc

        accH += p[0] * (leftP + p[1])  * lp[0];
        accH += p[1] * (p[0]  + p[2])  * lp[1];
        accH += p[2] * (p[1]  + p[3])  * lp[2];
        accH += p[3] * (p[2]  + rightP)* lp[3];

        dc = (l == 63) ? p[3] * lp[3] : 0.0f;
        prev_p3 = p[3];
    }
    // Row end: last chunk lane-63 right neighbor is 0 -> dc term drops.

    float total = (-tb * LN2) * (accH + invN * accL);

    // Pure in-wave reduction; lane 0 stores the row partial. No barriers.
#pragma unroll
    for (int off = 32; off; off >>= 1) total += __shfl_down(total, off);
    if (l == 0) partials[row_idx] = total;
}

// Mean over B row partials -> scalar. 512 threads, float4 loads.
__global__ __launch_bounds__(512) void reduce_mean_kernel(
        const float* __restrict__ part, float* __restrict__ out,
        int B, float invB) {
    const int nvec = B >> 2;
    float acc = 0.0f;
    for (int i = threadIdx.x; i < nvec; i += 512) {
        f4 v = reinterpret_cast<const f4*>(part)[i];
        acc += (v.x + v.y) + (v.z + v.w);
    }
#pragma unroll
    for (int off = 32; off; off >>= 1) acc += __shfl_down(acc, off);
    __shared__ float sm[8];
    if ((threadIdx.x & 63) == 0) sm[threadIdx.x >> 6] = acc;
    __syncthreads();
    if (threadIdx.x == 0) {
        float s = 0.0f;
#pragma unroll
        for (int wv = 0; wv < 8; ++wv) s += sm[wv];
        out[0] = s * invB;
    }
}

extern "C" void kernel_launch(void* const* d_in, const int* in_sizes, int n_in,
                              void* d_out, int out_size, void* d_ws, size_t ws_size,
                              hipStream_t stream) {
    const float* inputs  = (const float*)d_in[0];
    const float* targets = (const float*)d_in[1];
    float* out = (float*)d_out;

    const int B = in_sizes[1];                 // 8192 rows
    const int nblk = B / ROWS_PER_BLOCK;       // 2048 blocks

    float* partials = (float*)d_ws;            // B floats of scratch

    row_loss_kernel<<<nblk, 256, 0, stream>>>(
        inputs, targets, partials, 1.0f / (float)N_ELEM);
    reduce_mean_kernel<<<1, 512, 0, stream>>>(
        partials, out, B, 1.0f / (float)B);
}

// Round 7
// 29.240 us; speedup vs baseline: 9.1471x; 1.1125x over previous
//
#include <hip/hip_runtime.h>
#include <math.h>

typedef float f4 __attribute__((ext_vector_type(4)));

constexpr int N_ELEM = 4096;
constexpr int NCHUNK = 16;          // 16 chunks x 256 elems (64 lanes x float4)
constexpr int ROWS_PER_BLOCK = 4;   // one wave per row
constexpr int PF = 4;               // rolling prefetch window (dwordx4 in flight)
constexpr float LOG2E = 1.4426950408889634f;
constexpr float LN2   = 0.6931471805599453f;

// One WAVE per row; lane l, chunk c owns float4 at 256c + 4l (lane-contiguous,
// fully coalesced). Neighbor exchange via in-wave shuffles + deferred lane-63
// coefficient. Math in log2 domain; ln2 folded into the final scale:
//   m = -|x|*log2e, L2 = log2(1+2^m)
//   log2 p = min(x,0)*log2e - L2 ; p = 2^(log2 p) ; log2 p + log2(1-p) = m - 2*L2
// __launch_bounds__(256,8): force VGPR<=64 so all 8 blocks/CU are co-resident
// (2048 blocks = 256 CU x 8 -> single dispatch round).
__global__ __launch_bounds__(256, 8) void row_loss_kernel(
        const float* __restrict__ in,
        const float* __restrict__ tgt,
        float* __restrict__ partials,
        float invN) {
    const int t = threadIdx.x;
    const int w = t >> 6;
    const int l = t & 63;
    const int row_idx = blockIdx.x * ROWS_PER_BLOCK + w;
    const float* __restrict__ row = in + (size_t)row_idx * N_ELEM + (l << 2);

    const float tb = tgt[row_idx];   // wave-uniform -> scalar load

    f4 buf[PF];                      // statically indexed after unroll -> VGPRs
#pragma unroll
    for (int c = 0; c < PF; ++c)
        buf[c] = *reinterpret_cast<const f4*>(row + (c << 8));

    float accH = 0.0f;   // sum p*(p_left+p_right)*log2(p)
    float accL = 0.0f;   // sum log2 p + log2(1-p)
    float prev_p3 = 0.0f;
    float dc = 0.0f;     // lane-63 deferred coefficient p3*lp3

#pragma unroll
    for (int c = 0; c < NCHUNK; ++c) {
        f4 v = buf[c & (PF - 1)];
        if (c + PF < NCHUNK)         // refill the slot just consumed
            buf[c & (PF - 1)] = *reinterpret_cast<const f4*>(row + ((c + PF) << 8));

        float p[4], lp[4];
#pragma unroll
        for (int j = 0; j < 4; ++j) {
            float x   = v[j];
            float m   = -fabsf(x) * LOG2E;              // log2 e^{-|x|}
            float e2  = __builtin_amdgcn_exp2f(m);      // e^{-|x|}
            float L2  = __builtin_amdgcn_logf(1.0f + e2);  // log2(1+e^{-|x|})
            float lp2 = fmaf(fminf(x, 0.0f), LOG2E, -L2);  // log2 p
            p[j]  = __builtin_amdgcn_exp2f(lp2);        // sigmoid(x)
            lp[j] = lp2;
            accL += fmaf(-2.0f, L2, m);                 // log2 p + log2(1-p)
        }

        // Resolve prev chunk's lane-63 deferred right-neighbor term:
        // its right neighbor is this chunk's lane-0 p0.
        float b0 = __shfl(p[0], 0);
        accH += dc * b0;

        // In-wave neighbor exchange.
        float leftP  = __shfl_up(p[3], 1);       // lane l-1's p3 = p[idx-1]
        float rightP = __shfl_down(p[0], 1);     // lane l+1's p0 = p[idx+4]
        float p3b    = __shfl(prev_p3, 63);      // prev chunk lane-63's p3
        if (l == 0)  leftP  = (c == 0) ? 0.0f : p3b;   // row start pads 0
        if (l == 63) rightP = 0.0f;                     // deferred via dc

        accH += p[0] * (leftP + p[1])  * lp[0];
        accH += p[1] * (p[0]  + p[2])  * lp[1];
        accH += p[2] * (p[1]  + p[3])  * lp[2];
        accH += p[3] * (p[2]  + rightP)* lp[3];

        dc = (l == 63) ? p[3] * lp[3] : 0.0f;
        prev_p3 = p[3];
    }
    // Row end: last chunk lane-63 right neighbor is 0 -> dc term drops.

    float total = (-tb * LN2) * (accH + invN * accL);

    // In-wave reduce, then one tiny LDS combine -> per-BLOCK partial.
#pragma unroll
    for (int off = 32; off; off >>= 1) total += __shfl_down(total, off);

    __shared__ float sm[4];
    if (l == 0) sm[w] = total;
    __syncthreads();
    if (t == 0) partials[blockIdx.x] = (sm[0] + sm[1]) + (sm[2] + sm[3]);
}

// Mean over block partials (nblk = 2048) -> scalar.
__global__ __launch_bounds__(256) void reduce_mean_kernel(
        const float* __restrict__ part, float* __restrict__ out,
        int nblk, float invB) {
    const int nvec = nblk >> 2;
    float acc = 0.0f;
    for (int i = threadIdx.x; i < nvec; i += 256) {
        f4 v = reinterpret_cast<const f4*>(part)[i];
        acc += (v.x + v.y) + (v.z + v.w);
    }
#pragma unroll
    for (int off = 32; off; off >>= 1) acc += __shfl_down(acc, off);
    __shared__ float sm[4];
    if ((threadIdx.x & 63) == 0) sm[threadIdx.x >> 6] = acc;
    __syncthreads();
    if (threadIdx.x == 0) out[0] = ((sm[0] + sm[1]) + (sm[2] + sm[3])) * invB;
}

extern "C" void kernel_launch(void* const* d_in, const int* in_sizes, int n_in,
                              void* d_out, int out_size, void* d_ws, size_t ws_size,
                              hipStream_t stream) {
    const float* inputs  = (const float*)d_in[0];
    const float* targets = (const float*)d_in[1];
    float* out = (float*)d_out;

    const int B = in_sizes[1];                 // 8192 rows
    const int nblk = B / ROWS_PER_BLOCK;       // 2048 blocks

    float* partials = (float*)d_ws;            // nblk floats of scratch

    row_loss_kernel<<<nblk, 256, 0, stream>>>(
        inputs, targets, partials, 1.0f / (float)N_ELEM);
    reduce_mean_kernel<<<1, 256, 0, stream>>>(
        partials, out, nblk, 1.0f / (float)B);
}